// Round 1
// baseline (6721.415 us; speedup 1.0000x reference)
//
#include <hip/hip_runtime.h>

#define D_IN 128
#define D_H  128
#define D_OUT 64
#define TS 16

__global__ void k_deg_init(float* deg, int n) {
    int i = blockIdx.x * blockDim.x + threadIdx.x;
    if (i < n) deg[i] = 1.0f;   // self-loop
}

__global__ void k_deg_edges(const int* __restrict__ colv, float* deg, int E) {
    int e = blockIdx.x * blockDim.x + threadIdx.x;
    if (e < E) atomicAdd(&deg[colv[e]], 1.0f);
}

__global__ void k_dinv(float* deg, int n) {
    int i = blockIdx.x * blockDim.x + threadIdx.x;
    if (i < n) deg[i] = 1.0f / sqrtf(deg[i]);
}

// H[M, Dout] = X[M, K] @ W[Dout, K]^T   (f64 accumulation)
__global__ void k_gemm_xwt(const float* __restrict__ X, const float* __restrict__ W,
                           float* __restrict__ H, int M, int K, int Dout) {
    __shared__ float Xs[TS][TS + 1];
    __shared__ float Ws[TS][TS + 1];
    int tx = threadIdx.x, ty = threadIdx.y;
    int i = blockIdx.y * TS + ty;   // node row
    int j = blockIdx.x * TS + tx;   // output feature
    double acc = 0.0;
    for (int k0 = 0; k0 < K; k0 += TS) {
        Xs[ty][tx] = (i < M) ? X[(size_t)i * K + k0 + tx] : 0.0f;
        int jw = blockIdx.x * TS + ty;
        Ws[ty][tx] = (jw < Dout) ? W[(size_t)jw * K + k0 + tx] : 0.0f;
        __syncthreads();
        #pragma unroll
        for (int kk = 0; kk < TS; ++kk)
            acc += (double)Xs[ty][kk] * (double)Ws[tx][kk];
        __syncthreads();
    }
    if (i < M && j < Dout) H[(size_t)i * Dout + j] = (float)acc;
}

// AGG[i,:] = dinv[i]^2 * H[i,:]   (self-loop term, also initializes AGG)
template <typename T>
__global__ void k_agg_init(const float* __restrict__ H, const float* __restrict__ dinv,
                           T* __restrict__ AGG, int M, int D) {
    long long idx = (long long)blockIdx.x * blockDim.x + threadIdx.x;
    long long total = (long long)M * D;
    if (idx >= total) return;
    int i = (int)(idx / D);
    T w = (T)dinv[i] * (T)dinv[i];
    AGG[idx] = w * (T)H[idx];
}

// AGG[col,:] += dinv[row]*dinv[col] * H[row,:]   (32 or 16 lanes per edge, float4 each)
template <typename T>
__global__ void k_agg_edges(const int* __restrict__ row, const int* __restrict__ colv,
                            const float* __restrict__ dinv, const float* __restrict__ H,
                            T* __restrict__ AGG, int E, int D) {
    int t = blockIdx.x * blockDim.x + threadIdx.x;
    int lpe = D >> 2;               // float4 lanes per edge
    int e = t / lpe;
    int l = t - e * lpe;
    if (e >= E) return;
    int r = row[e], c = colv[e];
    T w = (T)dinv[r] * (T)dinv[c];
    const float4 hv = *reinterpret_cast<const float4*>(H + (size_t)r * D + 4 * l);
    T* out = AGG + (size_t)c * D + 4 * l;
    atomicAdd(out + 0, w * (T)hv.x);
    atomicAdd(out + 1, w * (T)hv.y);
    atomicAdd(out + 2, w * (T)hv.z);
    atomicAdd(out + 3, w * (T)hv.w);
}

// X[idx] = act(AGG[idx] + b[d])
template <typename T>
__global__ void k_bias_act(const T* __restrict__ AGG, const float* __restrict__ b,
                           float* __restrict__ X, int M, int D, int do_relu) {
    long long idx = (long long)blockIdx.x * blockDim.x + threadIdx.x;
    long long total = (long long)M * D;
    if (idx >= total) return;
    int d = (int)(idx & (D - 1));   // D is a power of two (128 or 64)
    float v = (float)(AGG[idx] + (T)b[d]);
    if (do_relu) v = fmaxf(v, 0.0f);
    X[idx] = v;
}

extern "C" void kernel_launch(void* const* d_in, const int* in_sizes, int n_in,
                              void* d_out, int out_size, void* d_ws, size_t ws_size,
                              hipStream_t stream) {
    const float* x  = (const float*)d_in[0];
    const int*   ei = (const int*)d_in[1];
    const float* W[4] = {(const float*)d_in[2], (const float*)d_in[4],
                         (const float*)d_in[6], (const float*)d_in[8]};
    const float* B[4] = {(const float*)d_in[3], (const float*)d_in[5],
                         (const float*)d_in[7], (const float*)d_in[9]};
    const int N = in_sizes[0] / D_IN;
    const int E = in_sizes[1] / 2;
    const int* row  = ei;        // sources
    const int* colv = ei + E;    // targets

    // workspace carve-up (element counts, 256-element aligned)
    size_t nPad   = ((size_t)N + 255) & ~(size_t)255;
    float* dinv   = (float*)d_ws;
    float* bufA   = dinv + nPad;                       // X buffer [N,128] f32
    float* bufB   = bufA + (size_t)N * D_H;            // H buffer [N,128] f32
    double* agg64 = (double*)(bufB + (size_t)N * D_H); // AGG [N,128] f64 (optional)
    // align agg64 to 8 bytes
    agg64 = (double*)(((uintptr_t)agg64 + 7) & ~(uintptr_t)7);

    size_t need64 = (uintptr_t)(agg64 + (size_t)N * D_H) - (uintptr_t)d_ws;
    bool use64 = (ws_size >= need64);

    const int TB = 256;
    // degrees -> dinv
    k_deg_init<<<(N + TB - 1) / TB, TB, 0, stream>>>(dinv, N);
    k_deg_edges<<<(E + TB - 1) / TB, TB, 0, stream>>>(colv, dinv, E);
    k_dinv<<<(N + TB - 1) / TB, TB, 0, stream>>>(dinv, N);

    dim3 gblk(TS, TS);
    auto run_layer = [&](const float* Xin, int K, int Dout, int li, float* Xout, int relu) {
        // GEMM: H = Xin @ W^T
        dim3 ggrid(Dout / TS, (N + TS - 1) / TS);
        k_gemm_xwt<<<ggrid, gblk, 0, stream>>>(Xin, W[li], bufB, N, K, Dout);
        long long totND = (long long)N * Dout;
        long long totE  = (long long)E * (Dout >> 2);
        if (use64) {
            k_agg_init<double><<<(totND + TB - 1) / TB, TB, 0, stream>>>(bufB, dinv, agg64, N, Dout);
            k_agg_edges<double><<<(totE + TB - 1) / TB, TB, 0, stream>>>(row, colv, dinv, bufB, agg64, E, Dout);
            k_bias_act<double><<<(totND + TB - 1) / TB, TB, 0, stream>>>(agg64, B[li], Xout, N, Dout, relu);
        } else {
            k_agg_init<float><<<(totND + TB - 1) / TB, TB, 0, stream>>>(bufB, dinv, Xout, N, Dout);
            k_agg_edges<float><<<(totE + TB - 1) / TB, TB, 0, stream>>>(row, colv, dinv, bufB, Xout, E, Dout);
            k_bias_act<float><<<(totND + TB - 1) / TB, TB, 0, stream>>>(Xout, B[li], Xout, N, Dout, relu);
        }
    };

    run_layer(x,    D_IN, D_H,  0, bufA, 1);
    run_layer(bufA, D_H,  D_H,  1, bufA, 1);
    run_layer(bufA, D_H,  D_H,  2, bufA, 1);
    run_layer(bufA, D_H,  D_OUT, 3, (float*)d_out, 0);
}

// Round 2
// 738.486 us; speedup vs baseline: 9.1016x; 9.1016x over previous
//
#include <hip/hip_runtime.h>

#define D_IN 128
#define D_H  128
#define D_OUT 64
#define TS 16

// ---------- degree / dinv ----------
__global__ void k_zero_i32(int* p, int n) {
    int i = blockIdx.x * blockDim.x + threadIdx.x;
    if (i < n) p[i] = 0;
}

__global__ void k_count(const int* __restrict__ colv, int* __restrict__ cnt, int E) {
    int e = blockIdx.x * blockDim.x + threadIdx.x;
    if (e < E) atomicAdd(&cnt[colv[e]], 1);
}

__global__ void k_dinv_from_cnt(const int* __restrict__ cnt, float* __restrict__ dinv, int n) {
    int i = blockIdx.x * blockDim.x + threadIdx.x;
    if (i < n) dinv[i] = (float)(1.0 / sqrt((double)(cnt[i] + 1)));  // +1 self-loop
}

// ---------- exclusive prefix sum over cnt -> rp (3 kernels) ----------
__global__ void k_scan_block(const int* __restrict__ cnt, int* __restrict__ rp,
                             int* __restrict__ bsum, int n) {
    __shared__ int sm[256];
    int t = threadIdx.x;
    int i = blockIdx.x * 256 + t;
    int v = (i < n) ? cnt[i] : 0;
    sm[t] = v;
    __syncthreads();
    for (int off = 1; off < 256; off <<= 1) {
        int x = sm[t];
        int y = (t >= off) ? sm[t - off] : 0;
        __syncthreads();
        sm[t] = x + y;
        __syncthreads();
    }
    if (i < n) rp[i] = sm[t] - v;             // block-local exclusive
    if (t == 255) bsum[blockIdx.x] = sm[t];   // block total
}

__global__ void k_scan_bsum(int* __restrict__ bsum, int nb) {  // nb <= 256
    __shared__ int sm[256];
    int t = threadIdx.x;
    int v = (t < nb) ? bsum[t] : 0;
    sm[t] = v;
    __syncthreads();
    for (int off = 1; off < 256; off <<= 1) {
        int x = sm[t];
        int y = (t >= off) ? sm[t - off] : 0;
        __syncthreads();
        sm[t] = x + y;
        __syncthreads();
    }
    if (t < nb) bsum[t] = sm[t] - v;          // exclusive
}

__global__ void k_scan_add(int* __restrict__ rp, const int* __restrict__ bsum, int n) {
    int i = blockIdx.x * blockDim.x + threadIdx.x;
    if (i < n) rp[i] += bsum[blockIdx.x * 256 / 256 == 0 ? 0 : 0];  // placeholder, replaced below
}

// correct version (256-thread blocks assumed)
__global__ void k_scan_add2(int* __restrict__ rp, const int* __restrict__ bsum, int n) {
    int i = blockIdx.x * 256 + threadIdx.x;
    if (i < n) rp[i] += bsum[blockIdx.x];
}

// ---------- CSR scatter ----------
__global__ void k_scatter(const int* __restrict__ row, const int* __restrict__ colv,
                          const float* __restrict__ dinv, const int* __restrict__ rp,
                          int* __restrict__ fill, int* __restrict__ csr_src,
                          float* __restrict__ csr_w, int E) {
    int e = blockIdx.x * blockDim.x + threadIdx.x;
    if (e >= E) return;
    int r = row[e], c = colv[e];
    int pos = rp[c] + atomicAdd(&fill[c], 1);
    csr_src[pos] = r;
    csr_w[pos] = dinv[r] * dinv[c];
}

// ---------- GEMM: H[M,Dout] = X[M,K] @ W[Dout,K]^T (f64 acc) ----------
__global__ void k_gemm_xwt(const float* __restrict__ X, const float* __restrict__ W,
                           float* __restrict__ H, int M, int K, int Dout) {
    __shared__ float Xs[TS][TS + 1];
    __shared__ float Ws[TS][TS + 1];
    int tx = threadIdx.x, ty = threadIdx.y;
    int i = blockIdx.y * TS + ty;
    int j = blockIdx.x * TS + tx;
    double acc = 0.0;
    for (int k0 = 0; k0 < K; k0 += TS) {
        Xs[ty][tx] = (i < M) ? X[(size_t)i * K + k0 + tx] : 0.0f;
        int jw = blockIdx.x * TS + ty;
        Ws[ty][tx] = (jw < Dout) ? W[(size_t)jw * K + k0 + tx] : 0.0f;
        __syncthreads();
        #pragma unroll
        for (int kk = 0; kk < TS; ++kk)
            acc += (double)Xs[ty][kk] * (double)Ws[tx][kk];
        __syncthreads();
    }
    if (i < M && j < Dout) H[(size_t)i * Dout + j] = (float)acc;
}

// ---------- gather-aggregate + bias + relu, 64 lanes per node ----------
template <int D>
__global__ void k_agg_gather(const float* __restrict__ H, const float* __restrict__ dinv,
                             const int* __restrict__ rp, const int* __restrict__ csr_src,
                             const float* __restrict__ csr_w, const float* __restrict__ b,
                             float* __restrict__ X, int N, int E, int do_relu) {
    int node = blockIdx.x * 4 + (threadIdx.x >> 6);
    int lane = threadIdx.x & 63;
    if (node >= N) return;
    int beg = rp[node];
    int end = (node == N - 1) ? E : rp[node + 1];
    float di = dinv[node];
    double wself = (double)di * (double)di;
    if (D == 128) {
        int d0 = lane * 2;
        const float2 hs = *reinterpret_cast<const float2*>(H + (size_t)node * D + d0);
        double a0 = wself * hs.x, a1 = wself * hs.y;
        for (int k = beg; k < end; ++k) {
            int s = csr_src[k];
            double w = (double)csr_w[k];
            const float2 hv = *reinterpret_cast<const float2*>(H + (size_t)s * D + d0);
            a0 += w * hv.x;
            a1 += w * hv.y;
        }
        float v0 = (float)(a0 + (double)b[d0]);
        float v1 = (float)(a1 + (double)b[d0 + 1]);
        if (do_relu) { v0 = fmaxf(v0, 0.0f); v1 = fmaxf(v1, 0.0f); }
        *reinterpret_cast<float2*>(X + (size_t)node * D + d0) = make_float2(v0, v1);
    } else {  // D == 64
        int d0 = lane;
        double a0 = wself * H[(size_t)node * D + d0];
        for (int k = beg; k < end; ++k) {
            int s = csr_src[k];
            double w = (double)csr_w[k];
            a0 += w * H[(size_t)s * D + d0];
        }
        float v0 = (float)(a0 + (double)b[d0]);
        if (do_relu) v0 = fmaxf(v0, 0.0f);
        X[(size_t)node * D + d0] = v0;
    }
}

extern "C" void kernel_launch(void* const* d_in, const int* in_sizes, int n_in,
                              void* d_out, int out_size, void* d_ws, size_t ws_size,
                              hipStream_t stream) {
    const float* x  = (const float*)d_in[0];
    const int*   ei = (const int*)d_in[1];
    const float* W[4] = {(const float*)d_in[2], (const float*)d_in[4],
                         (const float*)d_in[6], (const float*)d_in[8]};
    const float* B[4] = {(const float*)d_in[3], (const float*)d_in[5],
                         (const float*)d_in[7], (const float*)d_in[9]};
    const int N = in_sizes[0] / D_IN;
    const int E = in_sizes[1] / 2;
    const int* row  = ei;        // sources
    const int* colv = ei + E;    // targets

    // workspace carve-up
    size_t nPad = ((size_t)N + 255) & ~(size_t)255;
    size_t ePad = ((size_t)E + 255) & ~(size_t)255;
    float* dinv    = (float*)d_ws;
    int*   cnt     = (int*)(dinv + nPad);
    int*   bsum    = cnt + nPad;
    int*   rp      = bsum + 256;
    int*   csr_src = rp + nPad;
    float* csr_w   = (float*)(csr_src + ePad);
    float* bufA    = csr_w + ePad;
    float* bufB    = bufA + (size_t)N * D_H;

    const int TB = 256;
    int nbN = (N + TB - 1) / TB;
    int nbE = (E + TB - 1) / TB;

    // --- CSR build ---
    k_zero_i32<<<nbN, TB, 0, stream>>>(cnt, N);
    k_count<<<nbE, TB, 0, stream>>>(colv, cnt, E);
    k_dinv_from_cnt<<<nbN, TB, 0, stream>>>(cnt, dinv, N);
    k_scan_block<<<nbN, TB, 0, stream>>>(cnt, rp, bsum, N);
    k_scan_bsum<<<1, 256, 0, stream>>>(bsum, nbN);
    k_scan_add2<<<nbN, TB, 0, stream>>>(rp, bsum, N);
    k_zero_i32<<<nbN, TB, 0, stream>>>(cnt, N);   // reuse as fill counters
    k_scatter<<<nbE, TB, 0, stream>>>(row, colv, dinv, rp, cnt, csr_src, csr_w, E);

    dim3 gblk(TS, TS);
    int aggGrid = (N + 3) / 4;   // 4 nodes per 256-thread block

    auto run_layer = [&](const float* Xin, int K, int Dout, int li, float* Xout, int relu) {
        dim3 ggrid(Dout / TS, (N + TS - 1) / TS);
        k_gemm_xwt<<<ggrid, gblk, 0, stream>>>(Xin, W[li], bufB, N, K, Dout);
        if (Dout == 128)
            k_agg_gather<128><<<aggGrid, TB, 0, stream>>>(bufB, dinv, rp, csr_src, csr_w,
                                                          B[li], Xout, N, E, relu);
        else
            k_agg_gather<64><<<aggGrid, TB, 0, stream>>>(bufB, dinv, rp, csr_src, csr_w,
                                                         B[li], Xout, N, E, relu);
    };

    run_layer(x,    D_IN, D_H,   0, bufA, 1);
    run_layer(bufA, D_H,  D_H,   1, bufA, 1);
    run_layer(bufA, D_H,  D_H,   2, bufA, 1);
    run_layer(bufA, D_H,  D_OUT, 3, (float*)d_out, 0);
}

// Round 3
// 415.419 us; speedup vs baseline: 16.1798x; 1.7777x over previous
//
#include <hip/hip_runtime.h>

#define D_IN 128
#define D_H  128
#define D_OUT 64

// ---------- CSR build ----------
__global__ void k_zero_i32(int* p, int n) {
    int i = blockIdx.x * blockDim.x + threadIdx.x;
    if (i < n) p[i] = 0;
}

__global__ void k_count(const int* __restrict__ colv, int* __restrict__ cnt, int E) {
    int e = blockIdx.x * blockDim.x + threadIdx.x;
    if (e < E) atomicAdd(&cnt[colv[e]], 1);
}

__global__ void k_dinv_from_cnt(const int* __restrict__ cnt, float* __restrict__ dinv, int n) {
    int i = blockIdx.x * blockDim.x + threadIdx.x;
    if (i < n) dinv[i] = (float)(1.0 / sqrt((double)(cnt[i] + 1)));  // +1 self-loop
}

__global__ void k_scan_block(const int* __restrict__ cnt, int* __restrict__ rp,
                             int* __restrict__ bsum, int n) {
    __shared__ int sm[256];
    int t = threadIdx.x;
    int i = blockIdx.x * 256 + t;
    int v = (i < n) ? cnt[i] : 0;
    sm[t] = v;
    __syncthreads();
    for (int off = 1; off < 256; off <<= 1) {
        int x = sm[t];
        int y = (t >= off) ? sm[t - off] : 0;
        __syncthreads();
        sm[t] = x + y;
        __syncthreads();
    }
    if (i < n) rp[i] = sm[t] - v;
    if (t == 255) bsum[blockIdx.x] = sm[t];
}

__global__ void k_scan_bsum(int* __restrict__ bsum, int nb) {  // nb <= 256
    __shared__ int sm[256];
    int t = threadIdx.x;
    int v = (t < nb) ? bsum[t] : 0;
    sm[t] = v;
    __syncthreads();
    for (int off = 1; off < 256; off <<= 1) {
        int x = sm[t];
        int y = (t >= off) ? sm[t - off] : 0;
        __syncthreads();
        sm[t] = x + y;
        __syncthreads();
    }
    if (t < nb) bsum[t] = sm[t] - v;
}

__global__ void k_scan_add2(int* __restrict__ rp, const int* __restrict__ bsum, int n) {
    int i = blockIdx.x * 256 + threadIdx.x;
    if (i < n) rp[i] += bsum[blockIdx.x];
}

__global__ void k_scatter(const int* __restrict__ row, const int* __restrict__ colv,
                          const float* __restrict__ dinv, const int* __restrict__ rp,
                          int* __restrict__ fill, int* __restrict__ csr_src,
                          float* __restrict__ csr_w, int E) {
    int e = blockIdx.x * blockDim.x + threadIdx.x;
    if (e >= E) return;
    int r = row[e], c = colv[e];
    int pos = rp[c] + atomicAdd(&fill[c], 1);
    csr_src[pos] = r;
    csr_w[pos] = dinv[r] * dinv[c];
}

// ---------- GEMM: H[M,Dout] = X[M,128] @ W[Dout,128]^T ----------
// 64x64 tile / block of 256 threads; 4x4 register tile per thread.
// f32 FMA in k-chunks of 16, f64 accumulation across chunks.
__global__ __launch_bounds__(256, 2)
void k_gemm_xwt(const float* __restrict__ X, const float* __restrict__ W,
                float* __restrict__ H, int M, int Dout) {
    __shared__ float Xs[128][64];   // k-major
    __shared__ float Ws[128][64];   // k-major
    const int tid = threadIdx.x;
    const int row0 = blockIdx.y * 64;
    const int col0 = blockIdx.x * 64;

    {   // stage X^T: lane r covers one row, 8 float4 along k
        const int r = tid & 63;
        const int k4b = (tid >> 6) * 8;   // 0,8,16,24
        const int gr = row0 + r;
        const float* src = X + (size_t)gr * 128 + 4 * k4b;
        #pragma unroll
        for (int q = 0; q < 8; ++q) {
            float4 v = make_float4(0.f, 0.f, 0.f, 0.f);
            if (gr < M) v = *(const float4*)(src + 4 * q);
            const int k = 4 * (k4b + q);
            Xs[k + 0][r] = v.x; Xs[k + 1][r] = v.y;
            Xs[k + 2][r] = v.z; Xs[k + 3][r] = v.w;
        }
        const int gj = col0 + r;          // always < Dout (Dout % 64 == 0)
        const float* wsrc = W + (size_t)gj * 128 + 4 * k4b;
        #pragma unroll
        for (int q = 0; q < 8; ++q) {
            const float4 v = *(const float4*)(wsrc + 4 * q);
            const int k = 4 * (k4b + q);
            Ws[k + 0][gj - col0] = v.x; Ws[k + 1][gj - col0] = v.y;
            Ws[k + 2][gj - col0] = v.z; Ws[k + 3][gj - col0] = v.w;
        }
    }
    __syncthreads();

    const int tx = tid & 15, ty = tid >> 4;
    const int r0 = ty * 4, j0 = tx * 4;
    double acc[4][4] = {{0.0}};

    for (int kc = 0; kc < 128; kc += 16) {
        float c[4][4] = {{0.f}};
        #pragma unroll
        for (int kk = 0; kk < 16; ++kk) {
            const float4 xa = *(const float4*)&Xs[kc + kk][r0];
            const float4 wb = *(const float4*)&Ws[kc + kk][j0];
            c[0][0] += xa.x * wb.x; c[0][1] += xa.x * wb.y; c[0][2] += xa.x * wb.z; c[0][3] += xa.x * wb.w;
            c[1][0] += xa.y * wb.x; c[1][1] += xa.y * wb.y; c[1][2] += xa.y * wb.z; c[1][3] += xa.y * wb.w;
            c[2][0] += xa.z * wb.x; c[2][1] += xa.z * wb.y; c[2][2] += xa.z * wb.z; c[2][3] += xa.z * wb.w;
            c[3][0] += xa.w * wb.x; c[3][1] += xa.w * wb.y; c[3][2] += xa.w * wb.z; c[3][3] += xa.w * wb.w;
        }
        #pragma unroll
        for (int i = 0; i < 4; ++i)
            #pragma unroll
            for (int j = 0; j < 4; ++j)
                acc[i][j] += (double)c[i][j];
    }

    #pragma unroll
    for (int i = 0; i < 4; ++i) {
        const int gr = row0 + r0 + i;
        if (gr < M) {
            const float4 o = make_float4((float)acc[i][0], (float)acc[i][1],
                                         (float)acc[i][2], (float)acc[i][3]);
            *(float4*)(H + (size_t)gr * Dout + col0 + j0) = o;
        }
    }
}

// ---------- gather-aggregate + bias + relu; one 64-lane wave per node ----------
template <int D>
__global__ void k_agg_gather(const float* __restrict__ H, const float* __restrict__ dinv,
                             const int* __restrict__ rp, const int* __restrict__ csr_src,
                             const float* __restrict__ csr_w, const float* __restrict__ b,
                             float* __restrict__ X, int N, int E, int do_relu) {
    int node = blockIdx.x * 4 + (threadIdx.x >> 6);
    int lane = threadIdx.x & 63;
    if (node >= N) return;
    int beg = rp[node];
    int end = (node == N - 1) ? E : rp[node + 1];
    float di = dinv[node];
    double wself = (double)di * (double)di;
    if (D == 128) {
        const int d0 = lane * 2;
        const float2 hs = *(const float2*)(H + (size_t)node * D + d0);
        double a0 = wself * hs.x, a1 = wself * hs.y;
        double c0 = 0.0, c1 = 0.0;
        int k = beg;
        for (; k + 2 <= end; k += 2) {
            const int s0 = csr_src[k], s1 = csr_src[k + 1];
            const double w0 = (double)csr_w[k], w1 = (double)csr_w[k + 1];
            const float2 h0 = *(const float2*)(H + (size_t)s0 * D + d0);
            const float2 h1 = *(const float2*)(H + (size_t)s1 * D + d0);
            a0 += w0 * h0.x; a1 += w0 * h0.y;
            c0 += w1 * h1.x; c1 += w1 * h1.y;
        }
        if (k < end) {
            const int s = csr_src[k];
            const double w = (double)csr_w[k];
            const float2 hv = *(const float2*)(H + (size_t)s * D + d0);
            a0 += w * hv.x; a1 += w * hv.y;
        }
        a0 += c0; a1 += c1;
        float v0 = (float)(a0 + (double)b[d0]);
        float v1 = (float)(a1 + (double)b[d0 + 1]);
        if (do_relu) { v0 = fmaxf(v0, 0.0f); v1 = fmaxf(v1, 0.0f); }
        *(float2*)(X + (size_t)node * D + d0) = make_float2(v0, v1);
    } else {  // D == 64
        const int d0 = lane;
        double a0 = wself * H[(size_t)node * D + d0];
        double c0 = 0.0;
        int k = beg;
        for (; k + 2 <= end; k += 2) {
            const int s0 = csr_src[k], s1 = csr_src[k + 1];
            const double w0 = (double)csr_w[k], w1 = (double)csr_w[k + 1];
            a0 += w0 * H[(size_t)s0 * D + d0];
            c0 += w1 * H[(size_t)s1 * D + d0];
        }
        if (k < end)
            a0 += (double)csr_w[k] * H[(size_t)csr_src[k] * D + d0];
        a0 += c0;
        float v0 = (float)(a0 + (double)b[d0]);
        if (do_relu) v0 = fmaxf(v0, 0.0f);
        X[(size_t)node * D + d0] = v0;
    }
}

extern "C" void kernel_launch(void* const* d_in, const int* in_sizes, int n_in,
                              void* d_out, int out_size, void* d_ws, size_t ws_size,
                              hipStream_t stream) {
    const float* x  = (const float*)d_in[0];
    const int*   ei = (const int*)d_in[1];
    const float* W[4] = {(const float*)d_in[2], (const float*)d_in[4],
                         (const float*)d_in[6], (const float*)d_in[8]};
    const float* B[4] = {(const float*)d_in[3], (const float*)d_in[5],
                         (const float*)d_in[7], (const float*)d_in[9]};
    const int N = in_sizes[0] / D_IN;
    const int E = in_sizes[1] / 2;
    const int* row  = ei;        // sources
    const int* colv = ei + E;    // targets

    // workspace carve-up
    size_t nPad = ((size_t)N + 255) & ~(size_t)255;
    size_t ePad = ((size_t)E + 255) & ~(size_t)255;
    float* dinv    = (float*)d_ws;
    int*   cnt     = (int*)(dinv + nPad);
    int*   bsum    = cnt + nPad;
    int*   rp      = bsum + 256;
    int*   csr_src = rp + nPad;
    float* csr_w   = (float*)(csr_src + ePad);
    float* bufA    = csr_w + ePad;
    float* bufB    = bufA + (size_t)N * D_H;

    const int TB = 256;
    int nbN = (N + TB - 1) / TB;
    int nbE = (E + TB - 1) / TB;

    // --- CSR build ---
    k_zero_i32<<<nbN, TB, 0, stream>>>(cnt, N);
    k_count<<<nbE, TB, 0, stream>>>(colv, cnt, E);
    k_dinv_from_cnt<<<nbN, TB, 0, stream>>>(cnt, dinv, N);
    k_scan_block<<<nbN, TB, 0, stream>>>(cnt, rp, bsum, N);
    k_scan_bsum<<<1, 256, 0, stream>>>(bsum, nbN);
    k_scan_add2<<<nbN, TB, 0, stream>>>(rp, bsum, N);
    k_zero_i32<<<nbN, TB, 0, stream>>>(cnt, N);   // reuse as fill counters
    k_scatter<<<nbE, TB, 0, stream>>>(row, colv, dinv, rp, cnt, csr_src, csr_w, E);

    int aggGrid = (N + 3) / 4;

    auto run_layer = [&](const float* Xin, int Dout, int li, float* Xout, int relu) {
        dim3 ggrid(Dout / 64, (N + 63) / 64);
        k_gemm_xwt<<<ggrid, 256, 0, stream>>>(Xin, W[li], bufB, N, Dout);
        if (Dout == 128)
            k_agg_gather<128><<<aggGrid, TB, 0, stream>>>(bufB, dinv, rp, csr_src, csr_w,
                                                          B[li], Xout, N, E, relu);
        else
            k_agg_gather<64><<<aggGrid, TB, 0, stream>>>(bufB, dinv, rp, csr_src, csr_w,
                                                         B[li], Xout, N, E, relu);
    };

    run_layer(x,    D_H,   0, bufA, 1);
    run_layer(bufA, D_H,   1, bufA, 1);
    run_layer(bufA, D_H,   2, bufA, 1);
    run_layer(bufA, D_OUT, 3, (float*)d_out, 0);
}

// Round 4
// 385.788 us; speedup vs baseline: 17.4226x; 1.0768x over previous
//
#include <hip/hip_runtime.h>

#define D_IN 128
#define D_H  128
#define D_OUT 64

// ---------- CSR build ----------
__global__ void k_zero_i32(int* p, int n) {
    int i = blockIdx.x * blockDim.x + threadIdx.x;
    if (i < n) p[i] = 0;
}

__global__ void k_count(const int* __restrict__ colv, int* __restrict__ cnt, int E) {
    int e = blockIdx.x * blockDim.x + threadIdx.x;
    if (e < E) atomicAdd(&cnt[colv[e]], 1);
}

__global__ void k_dinv_from_cnt(const int* __restrict__ cnt, float* __restrict__ dinv, int n) {
    int i = blockIdx.x * blockDim.x + threadIdx.x;
    if (i < n) dinv[i] = (float)(1.0 / sqrt((double)(cnt[i] + 1)));  // +1 self-loop
}

__global__ void k_scan_block(const int* __restrict__ cnt, int* __restrict__ rp,
                             int* __restrict__ bsum, int n) {
    __shared__ int sm[256];
    int t = threadIdx.x;
    int i = blockIdx.x * 256 + t;
    int v = (i < n) ? cnt[i] : 0;
    sm[t] = v;
    __syncthreads();
    for (int off = 1; off < 256; off <<= 1) {
        int x = sm[t];
        int y = (t >= off) ? sm[t - off] : 0;
        __syncthreads();
        sm[t] = x + y;
        __syncthreads();
    }
    if (i < n) rp[i] = sm[t] - v;
    if (t == 255) bsum[blockIdx.x] = sm[t];
}

__global__ void k_scan_bsum(int* __restrict__ bsum, int nb) {  // nb <= 256
    __shared__ int sm[256];
    int t = threadIdx.x;
    int v = (t < nb) ? bsum[t] : 0;
    sm[t] = v;
    __syncthreads();
    for (int off = 1; off < 256; off <<= 1) {
        int x = sm[t];
        int y = (t >= off) ? sm[t - off] : 0;
        __syncthreads();
        sm[t] = x + y;
        __syncthreads();
    }
    if (t < nb) bsum[t] = sm[t] - v;
}

__global__ void k_scan_add2(int* __restrict__ rp, const int* __restrict__ bsum, int n) {
    int i = blockIdx.x * 256 + threadIdx.x;
    if (i < n) rp[i] += bsum[blockIdx.x];
}

__global__ void k_scatter(const int* __restrict__ row, const int* __restrict__ colv,
                          const float* __restrict__ dinv, const int* __restrict__ rp,
                          int* __restrict__ fill, int* __restrict__ csr_src,
                          float* __restrict__ csr_w, int E) {
    int e = blockIdx.x * blockDim.x + threadIdx.x;
    if (e >= E) return;
    int r = row[e], c = colv[e];
    int pos = rp[c] + atomicAdd(&fill[c], 1);
    csr_src[pos] = r;
    csr_w[pos] = dinv[r] * dinv[c];
}

// ---------- GEMM: H[M,Dout] = X[M,128] @ W[Dout,128]^T ----------
// 64x64 tile / 256 threads; 4x4 register tile; f32 FMA in k-chunks of 32,
// f64 accumulation across chunks.
__global__ __launch_bounds__(256, 2)
void k_gemm_xwt(const float* __restrict__ X, const float* __restrict__ W,
                float* __restrict__ H, int M, int Dout) {
    __shared__ float Xs[128][64];   // k-major
    __shared__ float Ws[128][64];   // k-major
    const int tid = threadIdx.x;
    const int row0 = blockIdx.y * 64;
    const int col0 = blockIdx.x * 64;

    {   // stage: lane r covers one row, 8 float4 along k
        const int r = tid & 63;
        const int k4b = (tid >> 6) * 8;   // 0,8,16,24
        const int gr = row0 + r;
        const float* src = X + (size_t)gr * 128 + 4 * k4b;
        #pragma unroll
        for (int q = 0; q < 8; ++q) {
            float4 v = make_float4(0.f, 0.f, 0.f, 0.f);
            if (gr < M) v = *(const float4*)(src + 4 * q);
            const int k = 4 * (k4b + q);
            Xs[k + 0][r] = v.x; Xs[k + 1][r] = v.y;
            Xs[k + 2][r] = v.z; Xs[k + 3][r] = v.w;
        }
        const int gj = col0 + r;          // always < Dout (Dout % 64 == 0)
        const float* wsrc = W + (size_t)gj * 128 + 4 * k4b;
        #pragma unroll
        for (int q = 0; q < 8; ++q) {
            const float4 v = *(const float4*)(wsrc + 4 * q);
            const int k = 4 * (k4b + q);
            Ws[k + 0][gj - col0] = v.x; Ws[k + 1][gj - col0] = v.y;
            Ws[k + 2][gj - col0] = v.z; Ws[k + 3][gj - col0] = v.w;
        }
    }
    __syncthreads();

    const int tx = tid & 15, ty = tid >> 4;
    const int r0 = ty * 4, j0 = tx * 4;
    double acc[4][4] = {{0.0}};

    for (int kc = 0; kc < 128; kc += 32) {
        float c[4][4] = {{0.f}};
        #pragma unroll
        for (int kk = 0; kk < 32; ++kk) {
            const float4 xa = *(const float4*)&Xs[kc + kk][r0];
            const float4 wb = *(const float4*)&Ws[kc + kk][j0];
            c[0][0] += xa.x * wb.x; c[0][1] += xa.x * wb.y; c[0][2] += xa.x * wb.z; c[0][3] += xa.x * wb.w;
            c[1][0] += xa.y * wb.x; c[1][1] += xa.y * wb.y; c[1][2] += xa.y * wb.z; c[1][3] += xa.y * wb.w;
            c[2][0] += xa.z * wb.x; c[2][1] += xa.z * wb.y; c[2][2] += xa.z * wb.z; c[2][3] += xa.z * wb.w;
            c[3][0] += xa.w * wb.x; c[3][1] += xa.w * wb.y; c[3][2] += xa.w * wb.z; c[3][3] += xa.w * wb.w;
        }
        #pragma unroll
        for (int i = 0; i < 4; ++i)
            #pragma unroll
            for (int j = 0; j < 4; ++j)
                acc[i][j] += (double)c[i][j];
    }

    #pragma unroll
    for (int i = 0; i < 4; ++i) {
        const int gr = row0 + r0 + i;
        if (gr < M) {
            const float4 o = make_float4((float)acc[i][0], (float)acc[i][1],
                                         (float)acc[i][2], (float)acc[i][3]);
            *(float4*)(H + (size_t)gr * Dout + col0 + j0) = o;
        }
    }
}

// ---------- gather-aggregate + bias + relu ----------
// One 64-lane wave per node. Edge (src,w) lists are batch-preloaded into lane
// registers (2 coalesced loads / 64 edges) and broadcast via shfl, so only the
// H-row gathers touch memory in the inner loop. Unroll x4 for MLP.
template <int D>
__global__ void k_agg_gather(const float* __restrict__ H, const float* __restrict__ dinv,
                             const int* __restrict__ rp, const int* __restrict__ csr_src,
                             const float* __restrict__ csr_w, const float* __restrict__ b,
                             float* __restrict__ X, int N, int E, int do_relu) {
    const int node = blockIdx.x * 4 + (threadIdx.x >> 6);
    const int lane = threadIdx.x & 63;
    if (node >= N) return;
    const int beg = rp[node];
    const int end = (node == N - 1) ? E : rp[node + 1];
    const int deg = end - beg;
    const float di = dinv[node];
    const double wself = (double)di * (double)di;

    if (D == 128) {
        const int d0 = lane * 2;
        double a0[4] = {0.0, 0.0, 0.0, 0.0};
        double a1[4] = {0.0, 0.0, 0.0, 0.0};
        {
            const float2 hs = *(const float2*)(H + (size_t)node * D + d0);
            a0[0] = wself * hs.x; a1[0] = wself * hs.y;
        }
        for (int base = 0; base < deg; base += 64) {
            const int m = min(64, deg - base);
            int s_l = 0; float w_l = 0.f;
            if (lane < m) {
                s_l = csr_src[beg + base + lane];
                w_l = csr_w[beg + base + lane];
            }
            int j = 0;
            for (; j + 4 <= m; j += 4) {
                const int s0 = __shfl(s_l, j + 0), s1 = __shfl(s_l, j + 1);
                const int s2 = __shfl(s_l, j + 2), s3 = __shfl(s_l, j + 3);
                const float w0 = __shfl(w_l, j + 0), w1 = __shfl(w_l, j + 1);
                const float w2 = __shfl(w_l, j + 2), w3 = __shfl(w_l, j + 3);
                const float2 h0 = *(const float2*)(H + (size_t)s0 * D + d0);
                const float2 h1 = *(const float2*)(H + (size_t)s1 * D + d0);
                const float2 h2 = *(const float2*)(H + (size_t)s2 * D + d0);
                const float2 h3 = *(const float2*)(H + (size_t)s3 * D + d0);
                a0[0] += (double)w0 * h0.x; a1[0] += (double)w0 * h0.y;
                a0[1] += (double)w1 * h1.x; a1[1] += (double)w1 * h1.y;
                a0[2] += (double)w2 * h2.x; a1[2] += (double)w2 * h2.y;
                a0[3] += (double)w3 * h3.x; a1[3] += (double)w3 * h3.y;
            }
            for (; j < m; ++j) {
                const int s = __shfl(s_l, j);
                const float w = __shfl(w_l, j);
                const float2 hv = *(const float2*)(H + (size_t)s * D + d0);
                a0[0] += (double)w * hv.x; a1[0] += (double)w * hv.y;
            }
        }
        const double A0 = (a0[0] + a0[1]) + (a0[2] + a0[3]);
        const double A1 = (a1[0] + a1[1]) + (a1[2] + a1[3]);
        float v0 = (float)(A0 + (double)b[d0]);
        float v1 = (float)(A1 + (double)b[d0 + 1]);
        if (do_relu) { v0 = fmaxf(v0, 0.0f); v1 = fmaxf(v1, 0.0f); }
        *(float2*)(X + (size_t)node * D + d0) = make_float2(v0, v1);
    } else {  // D == 64: two 32-lane halves, each half owns one edge per step
        const int half = lane >> 5;         // 0 or 1
        const int l32 = lane & 31;
        const int d0 = l32 * 2;             // 32 lanes x float2 = 64 floats
        double a0[2] = {0.0, 0.0};
        double a1[2] = {0.0, 0.0};
        if (half == 0) {
            const float2 hs = *(const float2*)(H + (size_t)node * D + d0);
            a0[0] = wself * hs.x; a1[0] = wself * hs.y;
        }
        for (int base = 0; base < deg; base += 64) {
            const int m = min(64, deg - base);
            int s_l = 0; float w_l = 0.f;
            if (lane < m) {
                s_l = csr_src[beg + base + lane];
                w_l = csr_w[beg + base + lane];
            }
            int j = 0;
            for (; j + 4 <= m; j += 4) {
                const int e0 = j + half, e1 = j + 2 + half;
                const int s0 = __shfl(s_l, e0), s1 = __shfl(s_l, e1);
                const float w0 = __shfl(w_l, e0), w1 = __shfl(w_l, e1);
                const float2 h0 = *(const float2*)(H + (size_t)s0 * D + d0);
                const float2 h1 = *(const float2*)(H + (size_t)s1 * D + d0);
                a0[0] += (double)w0 * h0.x; a1[0] += (double)w0 * h0.y;
                a0[1] += (double)w1 * h1.x; a1[1] += (double)w1 * h1.y;
            }
            // tail: up to 3 edges
            {
                const int e0 = j + half;
                if (e0 < m) {
                    const int s = __shfl(s_l, e0);
                    const float w = __shfl(w_l, e0);
                    const float2 hv = *(const float2*)(H + (size_t)s * D + d0);
                    a0[0] += (double)w * hv.x; a1[0] += (double)w * hv.y;
                }
                const int e1 = j + 2 + half;
                if (e1 < m) {
                    const int s = __shfl(s_l, e1);
                    const float w = __shfl(w_l, e1);
                    const float2 hv = *(const float2*)(H + (size_t)s * D + d0);
                    a0[1] += (double)w * hv.x; a1[1] += (double)w * hv.y;
                }
            }
        }
        double A0 = a0[0] + a0[1];
        double A1 = a1[0] + a1[1];
        A0 += __shfl_xor(A0, 32);
        A1 += __shfl_xor(A1, 32);
        if (half == 0) {
            float v0 = (float)(A0 + (double)b[d0]);
            float v1 = (float)(A1 + (double)b[d0 + 1]);
            if (do_relu) { v0 = fmaxf(v0, 0.0f); v1 = fmaxf(v1, 0.0f); }
            *(float2*)(X + (size_t)node * D + d0) = make_float2(v0, v1);
        }
    }
}

extern "C" void kernel_launch(void* const* d_in, const int* in_sizes, int n_in,
                              void* d_out, int out_size, void* d_ws, size_t ws_size,
                              hipStream_t stream) {
    const float* x  = (const float*)d_in[0];
    const int*   ei = (const int*)d_in[1];
    const float* W[4] = {(const float*)d_in[2], (const float*)d_in[4],
                         (const float*)d_in[6], (const float*)d_in[8]};
    const float* B[4] = {(const float*)d_in[3], (const float*)d_in[5],
                         (const float*)d_in[7], (const float*)d_in[9]};
    const int N = in_sizes[0] / D_IN;
    const int E = in_sizes[1] / 2;
    const int* row  = ei;        // sources
    const int* colv = ei + E;    // targets

    // workspace carve-up
    size_t nPad = ((size_t)N + 255) & ~(size_t)255;
    size_t ePad = ((size_t)E + 255) & ~(size_t)255;
    float* dinv    = (float*)d_ws;
    int*   cnt     = (int*)(dinv + nPad);
    int*   bsum    = cnt + nPad;
    int*   rp      = bsum + 256;
    int*   csr_src = rp + nPad;
    float* csr_w   = (float*)(csr_src + ePad);
    float* bufA    = csr_w + ePad;
    float* bufB    = bufA + (size_t)N * D_H;

    const int TB = 256;
    int nbN = (N + TB - 1) / TB;
    int nbE = (E + TB - 1) / TB;

    // --- CSR build ---
    k_zero_i32<<<nbN, TB, 0, stream>>>(cnt, N);
    k_count<<<nbE, TB, 0, stream>>>(colv, cnt, E);
    k_dinv_from_cnt<<<nbN, TB, 0, stream>>>(cnt, dinv, N);
    k_scan_block<<<nbN, TB, 0, stream>>>(cnt, rp, bsum, N);
    k_scan_bsum<<<1, 256, 0, stream>>>(bsum, nbN);
    k_scan_add2<<<nbN, TB, 0, stream>>>(rp, bsum, N);
    k_zero_i32<<<nbN, TB, 0, stream>>>(cnt, N);   // reuse as fill counters
    k_scatter<<<nbE, TB, 0, stream>>>(row, colv, dinv, rp, cnt, csr_src, csr_w, E);

    int aggGrid = (N + 3) / 4;

    auto run_layer = [&](const float* Xin, int Dout, int li, float* Xout, int relu) {
        dim3 ggrid(Dout / 64, (N + 63) / 64);
        k_gemm_xwt<<<ggrid, 256, 0, stream>>>(Xin, W[li], bufB, N, Dout);
        if (Dout == 128)
            k_agg_gather<128><<<aggGrid, TB, 0, stream>>>(bufB, dinv, rp, csr_src, csr_w,
                                                          B[li], Xout, N, E, relu);
        else
            k_agg_gather<64><<<aggGrid, TB, 0, stream>>>(bufB, dinv, rp, csr_src, csr_w,
                                                         B[li], Xout, N, E, relu);
    };

    run_layer(x,    D_H,   0, bufA, 1);
    run_layer(bufA, D_H,   1, bufA, 1);
    run_layer(bufA, D_H,   2, bufA, 1);
    run_layer(bufA, D_OUT, 3, (float*)d_out, 0);
}

// Round 5
// 336.492 us; speedup vs baseline: 19.9750x; 1.1465x over previous
//
#include <hip/hip_runtime.h>

#define D_INF 128
#define D_HF  128
#define D_OUTF 64

typedef __attribute__((ext_vector_type(8))) short bf16x8;
typedef __attribute__((ext_vector_type(4))) float f32x4;
typedef unsigned short u16;
typedef unsigned int   u32;

__device__ inline u16 f2bf(float f) {
    u32 u = __float_as_uint(f);
    u32 r = (u + 0x7fffu + ((u >> 16) & 1u)) >> 16;   // RNE
    return (u16)r;
}
__device__ inline float bf2f(u16 h) { return __uint_as_float(((u32)h) << 16); }

// ---------- CSR build ----------
__global__ void k_zero_i32(int* p, int n) {
    int i = blockIdx.x * blockDim.x + threadIdx.x;
    if (i < n) p[i] = 0;
}

__global__ void k_count(const int* __restrict__ colv, int* __restrict__ cnt, int E) {
    int e = blockIdx.x * blockDim.x + threadIdx.x;
    if (e < E) atomicAdd(&cnt[colv[e]], 1);
}

__global__ void k_dinv_from_cnt(const int* __restrict__ cnt, float* __restrict__ dinv, int n) {
    int i = blockIdx.x * blockDim.x + threadIdx.x;
    if (i < n) dinv[i] = (float)(1.0 / sqrt((double)(cnt[i] + 1)));  // +1 self-loop
}

__global__ void k_scan_block(const int* __restrict__ cnt, int* __restrict__ rp,
                             int* __restrict__ bsum, int n) {
    __shared__ int sm[256];
    int t = threadIdx.x;
    int i = blockIdx.x * 256 + t;
    int v = (i < n) ? cnt[i] : 0;
    sm[t] = v;
    __syncthreads();
    for (int off = 1; off < 256; off <<= 1) {
        int x = sm[t];
        int y = (t >= off) ? sm[t - off] : 0;
        __syncthreads();
        sm[t] = x + y;
        __syncthreads();
    }
    if (i < n) rp[i] = sm[t] - v;
    if (t == 255) bsum[blockIdx.x] = sm[t];
}

__global__ void k_scan_bsum(int* __restrict__ bsum, int nb) {  // nb <= 256
    __shared__ int sm[256];
    int t = threadIdx.x;
    int v = (t < nb) ? bsum[t] : 0;
    sm[t] = v;
    __syncthreads();
    for (int off = 1; off < 256; off <<= 1) {
        int x = sm[t];
        int y = (t >= off) ? sm[t - off] : 0;
        __syncthreads();
        sm[t] = x + y;
        __syncthreads();
    }
    if (t < nb) bsum[t] = sm[t] - v;
}

__global__ void k_scan_add2(int* __restrict__ rp, const int* __restrict__ bsum, int n) {
    int i = blockIdx.x * 256 + threadIdx.x;
    if (i < n) rp[i] += bsum[blockIdx.x];
}

__global__ void k_scatter(const int* __restrict__ row, const int* __restrict__ colv,
                          const float* __restrict__ dinv, const int* __restrict__ rp,
                          int* __restrict__ fill, int* __restrict__ csr_src,
                          float* __restrict__ csr_w, int E) {
    int e = blockIdx.x * blockDim.x + threadIdx.x;
    if (e >= E) return;
    int r = row[e], c = colv[e];
    int pos = rp[c] + atomicAdd(&fill[c], 1);
    csr_src[pos] = r;
    csr_w[pos] = dinv[r] * dinv[c];
}

// ---------- f32 -> bf16 hi|lo split ----------
// Xcat[row][0..127]=hi, [128..255]=lo ; pad rows zeroed.
__global__ void k_split_x(const float* __restrict__ x, u16* __restrict__ Xcat,
                          int Nreal, int Mpad) {
    int idx = blockIdx.x * 256 + threadIdx.x;      // one thread per 4 elements
    int total = Mpad * 32;
    if (idx >= total) return;
    const int row = idx >> 5, c4 = (idx & 31) * 4;
    float4 v = make_float4(0.f, 0.f, 0.f, 0.f);
    if (row < Nreal) v = *(const float4*)(x + (size_t)row * 128 + c4);
    u16 h0 = f2bf(v.x), h1 = f2bf(v.y), h2 = f2bf(v.z), h3 = f2bf(v.w);
    u16 l0 = f2bf(v.x - bf2f(h0)), l1 = f2bf(v.y - bf2f(h1));
    u16 l2 = f2bf(v.z - bf2f(h2)), l3 = f2bf(v.w - bf2f(h3));
    u16* dst = Xcat + (size_t)row * 256 + c4;
    *(u32*)(dst)       = (u32)h0 | ((u32)h1 << 16);
    *(u32*)(dst + 2)   = (u32)h2 | ((u32)h3 << 16);
    *(u32*)(dst + 128) = (u32)l0 | ((u32)l1 << 16);
    *(u32*)(dst + 130) = (u32)l2 | ((u32)l3 << 16);
}

// all 4 weight matrices -> Wcat slabs of [128][256] each (layer 3 uses rows 0..63)
__global__ void k_split_w(const float* __restrict__ W0, const float* __restrict__ W1,
                          const float* __restrict__ W2, const float* __restrict__ W3,
                          u16* __restrict__ Wcat) {
    const int l = blockIdx.y;
    const float* W = (l == 0) ? W0 : (l == 1) ? W1 : (l == 2) ? W2 : W3;
    const int rows = (l == 3) ? 64 : 128;
    int idx = blockIdx.x * 256 + threadIdx.x;
    if (idx >= rows * 128) return;
    const int r = idx >> 7, c = idx & 127;
    float v = W[idx];
    u16 h = f2bf(v);
    u16 lo = f2bf(v - bf2f(h));
    u16* dst = Wcat + (size_t)l * 128 * 256 + (size_t)r * 256 + c;
    dst[0]   = h;
    dst[128] = lo;
}

// ---------- MFMA GEMM: H[Mpad,Dout] = Xcat[Mpad,256] @ Wcat[Dout,256]^T ----------
// BM=128, 4 waves. FM=4: Dout=128, waves 2x2 (wave tile 64x64).
//                  FM=2: Dout=64,  waves 4x1 (wave tile 32x64).
// No LDS: MFMA fragments are 16B-contiguous in row-major [row][k] for BOTH
// operands (A: row=lane&15,k=(lane>>4)*8; B: col=lane&15, same k).
template <int FM>
__global__ __launch_bounds__(256)
void k_gemm_mfma(const u16* __restrict__ Xcat, const u16* __restrict__ Wcat,
                 float* __restrict__ H) {
    constexpr int Dout = (FM == 4) ? 128 : 64;
    const int tid = threadIdx.x;
    const int wave = tid >> 6, lane = tid & 63;
    const int wm = (FM == 4) ? (wave >> 1) : wave;
    const int wn = (FM == 4) ? (wave & 1) : 0;
    const int row_base = blockIdx.x * 128 + wm * (FM * 16);
    const int col_base = wn * 64;
    const int lr = lane & 15;
    const int kg = lane >> 4;       // k-group (0..3)

    f32x4 acc[FM][4] = {};

    #pragma unroll 2
    for (int ks = 0; ks < 8; ++ks) {
        const int k0 = ks * 32 + kg * 8;
        bf16x8 a[FM], b[4];
        #pragma unroll
        for (int i = 0; i < FM; ++i)
            a[i] = *(const bf16x8*)(Xcat + (size_t)(row_base + i * 16 + lr) * 256 + k0);
        #pragma unroll
        for (int j = 0; j < 4; ++j)
            b[j] = *(const bf16x8*)(Wcat + (size_t)(col_base + j * 16 + lr) * 256 + k0);
        #pragma unroll
        for (int i = 0; i < FM; ++i)
            #pragma unroll
            for (int j = 0; j < 4; ++j)
                acc[i][j] = __builtin_amdgcn_mfma_f32_16x16x32_bf16(a[i], b[j], acc[i][j], 0, 0, 0);
    }

    #pragma unroll
    for (int i = 0; i < FM; ++i) {
        const int r0 = row_base + i * 16 + kg * 4;
        #pragma unroll
        for (int j = 0; j < 4; ++j) {
            const int c = col_base + j * 16 + lr;
            #pragma unroll
            for (int q = 0; q < 4; ++q)
                H[(size_t)(r0 + q) * Dout + c] = acc[i][j][q];
        }
    }
}

// ---------- gather-aggregate + bias (+relu) ----------
// One 64-lane wave per node; (src,w) batch-preloaded + shfl-broadcast; 8 edges
// in flight; f64 accumulation. OUT_MODE 1: relu + write bf16 hi|lo Xcat.
// OUT_MODE 0: write f32 (final layer, no relu).
template <int D, int OUT_MODE>
__global__ void k_agg_gather(const float* __restrict__ H, const float* __restrict__ dinv,
                             const int* __restrict__ rp, const int* __restrict__ csr_src,
                             const float* __restrict__ csr_w, const float* __restrict__ b,
                             void* __restrict__ out, int N, int E) {
    const int node = blockIdx.x * 4 + (threadIdx.x >> 6);
    const int lane = threadIdx.x & 63;
    if (node >= N) return;
    const int beg = rp[node];
    const int end = (node == N - 1) ? E : rp[node + 1];
    const int deg = end - beg;
    const float di = dinv[node];
    const double wself = (double)di * (double)di;

    if (D == 128) {
        const int d0 = lane * 2;
        double a0[8] = {}, a1[8] = {};
        {
            const float2 hs = *(const float2*)(H + (size_t)node * D + d0);
            a0[0] = wself * hs.x; a1[0] = wself * hs.y;
        }
        for (int base = 0; base < deg; base += 64) {
            const int m = min(64, deg - base);
            int s_l = 0; float w_l = 0.f;
            if (lane < m) {
                s_l = csr_src[beg + base + lane];
                w_l = csr_w[beg + base + lane];
            }
            int j = 0;
            for (; j + 8 <= m; j += 8) {
                int s[8]; float w[8];
                #pragma unroll
                for (int q = 0; q < 8; ++q) {
                    s[q] = __shfl(s_l, j + q);
                    w[q] = __shfl(w_l, j + q);
                }
                float2 h[8];
                #pragma unroll
                for (int q = 0; q < 8; ++q)
                    h[q] = *(const float2*)(H + (size_t)s[q] * D + d0);
                #pragma unroll
                for (int q = 0; q < 8; ++q) {
                    a0[q] += (double)w[q] * h[q].x;
                    a1[q] += (double)w[q] * h[q].y;
                }
            }
            for (; j < m; ++j) {
                const int s = __shfl(s_l, j);
                const float w = __shfl(w_l, j);
                const float2 hv = *(const float2*)(H + (size_t)s * D + d0);
                a0[0] += (double)w * hv.x; a1[0] += (double)w * hv.y;
            }
        }
        double A0 = ((a0[0] + a0[1]) + (a0[2] + a0[3])) + ((a0[4] + a0[5]) + (a0[6] + a0[7]));
        double A1 = ((a1[0] + a1[1]) + (a1[2] + a1[3])) + ((a1[4] + a1[5]) + (a1[6] + a1[7]));
        float v0 = (float)(A0 + (double)b[d0]);
        float v1 = (float)(A1 + (double)b[d0 + 1]);
        if (OUT_MODE == 1) {
            v0 = fmaxf(v0, 0.0f); v1 = fmaxf(v1, 0.0f);
            const u16 h0 = f2bf(v0), h1 = f2bf(v1);
            const u16 l0 = f2bf(v0 - bf2f(h0)), l1 = f2bf(v1 - bf2f(h1));
            u16* xc = (u16*)out + (size_t)node * 256 + d0;
            *(u32*)(xc)       = (u32)h0 | ((u32)h1 << 16);
            *(u32*)(xc + 128) = (u32)l0 | ((u32)l1 << 16);
        } else {
            *(float2*)((float*)out + (size_t)node * D + d0) = make_float2(v0, v1);
        }
    } else {  // D == 64: two 32-lane halves, 8-edge blocks, 4 edges per half
        const int half = lane >> 5;
        const int l32 = lane & 31;
        const int d0 = l32 * 2;
        double a0[4] = {}, a1[4] = {};
        if (half == 0) {
            const float2 hs = *(const float2*)(H + (size_t)node * D + d0);
            a0[0] = wself * hs.x; a1[0] = wself * hs.y;
        }
        for (int base = 0; base < deg; base += 64) {
            const int m = min(64, deg - base);
            int s_l = 0; float w_l = 0.f;
            if (lane < m) {
                s_l = csr_src[beg + base + lane];
                w_l = csr_w[beg + base + lane];
            }
            int j = 0;
            for (; j + 8 <= m; j += 8) {
                int s[4]; float w[4];
                #pragma unroll
                for (int q = 0; q < 4; ++q) {
                    s[q] = __shfl(s_l, j + 2 * q + half);
                    w[q] = __shfl(w_l, j + 2 * q + half);
                }
                float2 h[4];
                #pragma unroll
                for (int q = 0; q < 4; ++q)
                    h[q] = *(const float2*)(H + (size_t)s[q] * D + d0);
                #pragma unroll
                for (int q = 0; q < 4; ++q) {
                    a0[q] += (double)w[q] * h[q].x;
                    a1[q] += (double)w[q] * h[q].y;
                }
            }
            for (; j < m; j += 2) {   // tail in pairs split across halves
                const int e = j + half;
                if (e < m) {
                    const int s = __shfl(s_l, e);
                    const float w = __shfl(w_l, e);
                    const float2 hv = *(const float2*)(H + (size_t)s * D + d0);
                    a0[0] += (double)w * hv.x; a1[0] += (double)w * hv.y;
                }
            }
        }
        double A0 = (a0[0] + a0[1]) + (a0[2] + a0[3]);
        double A1 = (a1[0] + a1[1]) + (a1[2] + a1[3]);
        A0 += __shfl_xor(A0, 32);
        A1 += __shfl_xor(A1, 32);
        if (half == 0) {
            float v0 = (float)(A0 + (double)b[d0]);
            float v1 = (float)(A1 + (double)b[d0 + 1]);
            *(float2*)((float*)out + (size_t)node * D + d0) = make_float2(v0, v1);
        }
    }
}

extern "C" void kernel_launch(void* const* d_in, const int* in_sizes, int n_in,
                              void* d_out, int out_size, void* d_ws, size_t ws_size,
                              hipStream_t stream) {
    const float* x  = (const float*)d_in[0];
    const int*   ei = (const int*)d_in[1];
    const float* W[4] = {(const float*)d_in[2], (const float*)d_in[4],
                         (const float*)d_in[6], (const float*)d_in[8]};
    const float* B[4] = {(const float*)d_in[3], (const float*)d_in[5],
                         (const float*)d_in[7], (const float*)d_in[9]};
    const int N = in_sizes[0] / D_INF;
    const int E = in_sizes[1] / 2;
    const int Mpad = (N + 127) & ~127;
    const int* row  = ei;        // sources
    const int* colv = ei + E;    // targets

    // workspace carve-up
    size_t nPad = ((size_t)N + 255) & ~(size_t)255;
    size_t ePad = ((size_t)E + 255) & ~(size_t)255;
    float* dinv    = (float*)d_ws;
    int*   cnt     = (int*)(dinv + nPad);
    int*   bsum    = cnt + nPad;
    int*   rp      = bsum + 256;
    int*   csr_src = rp + nPad;
    float* csr_w   = (float*)(csr_src + ePad);
    float* Hbuf    = csr_w + ePad;                       // [Mpad][128] f32
    u16*   Xcat    = (u16*)(Hbuf + (size_t)Mpad * 128);  // [Mpad][256] bf16
    u16*   Wcat    = Xcat + (size_t)Mpad * 256;          // 4 x [128][256] bf16

    const int TB = 256;
    int nbN = (N + TB - 1) / TB;
    int nbE = (E + TB - 1) / TB;

    // --- CSR build ---
    k_zero_i32<<<nbN, TB, 0, stream>>>(cnt, N);
    k_count<<<nbE, TB, 0, stream>>>(colv, cnt, E);
    k_dinv_from_cnt<<<nbN, TB, 0, stream>>>(cnt, dinv, N);
    k_scan_block<<<nbN, TB, 0, stream>>>(cnt, rp, bsum, N);
    k_scan_bsum<<<1, 256, 0, stream>>>(bsum, nbN);
    k_scan_add2<<<nbN, TB, 0, stream>>>(rp, bsum, N);
    k_zero_i32<<<nbN, TB, 0, stream>>>(cnt, N);   // reuse as fill counters
    k_scatter<<<nbE, TB, 0, stream>>>(row, colv, dinv, rp, cnt, csr_src, csr_w, E);

    // --- bf16 splits ---
    k_split_x<<<(Mpad * 32 + TB - 1) / TB, TB, 0, stream>>>(x, Xcat, N, Mpad);
    {
        dim3 g(64, 4);   // 64 blocks cover 128*128 elems; layer 3 guarded
        k_split_w<<<g, TB, 0, stream>>>(W[0], W[1], W[2], W[3], Wcat);
    }

    const int aggGrid = (N + 3) / 4;
    const int gemmGrid = Mpad / 128;

    // layers 0..2 : GEMM(128) -> gather -> Xcat(bf16 split)
    for (int l = 0; l < 3; ++l) {
        k_gemm_mfma<4><<<gemmGrid, 256, 0, stream>>>(Xcat, Wcat + (size_t)l * 128 * 256, Hbuf);
        k_agg_gather<128, 1><<<aggGrid, TB, 0, stream>>>(Hbuf, dinv, rp, csr_src, csr_w,
                                                         B[l], (void*)Xcat, N, E);
    }
    // layer 3 : GEMM(64) -> gather -> d_out (f32)
    k_gemm_mfma<2><<<gemmGrid, 256, 0, stream>>>(Xcat, Wcat + (size_t)3 * 128 * 256, Hbuf);
    k_agg_gather<64, 0><<<aggGrid, TB, 0, stream>>>(Hbuf, dinv, rp, csr_src, csr_w,
                                                    B[3], d_out, N, E);
}

// Round 6
// 331.922 us; speedup vs baseline: 20.2500x; 1.0138x over previous
//
#include <hip/hip_runtime.h>

#define D_INF 128
#define D_HF  128
#define D_OUTF 64

typedef __attribute__((ext_vector_type(8))) short bf16x8;
typedef __attribute__((ext_vector_type(4))) float f32x4;
typedef unsigned short u16;
typedef unsigned int   u32;

__device__ inline u16 f2bf(float f) {
    u32 u = __float_as_uint(f);
    u32 r = (u + 0x7fffu + ((u >> 16) & 1u)) >> 16;   // RNE
    return (u16)r;
}
__device__ inline float bf2f(u16 h) { return __uint_as_float(((u32)h) << 16); }

// ---------- CSR build ----------
__global__ void k_zero_i32(int* p, int n) {
    int i = blockIdx.x * blockDim.x + threadIdx.x;
    if (i < n) p[i] = 0;
}

__global__ void k_count(const int* __restrict__ colv, int* __restrict__ cnt, int E) {
    int e = blockIdx.x * blockDim.x + threadIdx.x;
    if (e < E) atomicAdd(&cnt[colv[e]], 1);
}

// scan (block-local) + dinv + re-zero cnt for reuse as fill counters
__global__ void k_scan_block(int* __restrict__ cnt, int* __restrict__ rp,
                             int* __restrict__ bsum, float* __restrict__ dinv, int n) {
    __shared__ int sm[256];
    int t = threadIdx.x;
    int i = blockIdx.x * 256 + t;
    int v = (i < n) ? cnt[i] : 0;
    sm[t] = v;
    __syncthreads();
    for (int off = 1; off < 256; off <<= 1) {
        int x = sm[t];
        int y = (t >= off) ? sm[t - off] : 0;
        __syncthreads();
        sm[t] = x + y;
        __syncthreads();
    }
    if (i < n) {
        rp[i] = sm[t] - v;
        dinv[i] = (float)(1.0 / sqrt((double)(v + 1)));   // +1 self-loop
        cnt[i] = 0;                                        // fill counter reset
    }
    if (t == 255) bsum[blockIdx.x] = sm[t];
}

__global__ void k_scan_bsum(int* __restrict__ bsum, int nb) {  // nb <= 256
    __shared__ int sm[256];
    int t = threadIdx.x;
    int v = (t < nb) ? bsum[t] : 0;
    sm[t] = v;
    __syncthreads();
    for (int off = 1; off < 256; off <<= 1) {
        int x = sm[t];
        int y = (t >= off) ? sm[t - off] : 0;
        __syncthreads();
        sm[t] = x + y;
        __syncthreads();
    }
    if (t < nb) bsum[t] = sm[t] - v;
}

__global__ void k_scan_add2(int* __restrict__ rp, const int* __restrict__ bsum, int n) {
    int i = blockIdx.x * 256 + threadIdx.x;
    if (i < n) rp[i] += bsum[blockIdx.x];
}

__global__ void k_scatter(const int* __restrict__ row, const int* __restrict__ colv,
                          const float* __restrict__ dinv, const int* __restrict__ rp,
                          int* __restrict__ fill, int* __restrict__ csr_src,
                          float* __restrict__ csr_w, int E) {
    int e = blockIdx.x * blockDim.x + threadIdx.x;
    if (e >= E) return;
    int r = row[e], c = colv[e];
    int pos = rp[c] + atomicAdd(&fill[c], 1);
    csr_src[pos] = r;
    csr_w[pos] = dinv[r] * dinv[c];
}

// ---------- f32 -> bf16 hi|lo split ----------
__global__ void k_split_x(const float* __restrict__ x, u16* __restrict__ Xcat,
                          int Nreal, int Mpad) {
    int idx = blockIdx.x * 256 + threadIdx.x;      // one thread per 4 elements
    int total = Mpad * 32;
    if (idx >= total) return;
    const int row = idx >> 5, c4 = (idx & 31) * 4;
    float4 v = make_float4(0.f, 0.f, 0.f, 0.f);
    if (row < Nreal) v = *(const float4*)(x + (size_t)row * 128 + c4);
    u16 h0 = f2bf(v.x), h1 = f2bf(v.y), h2 = f2bf(v.z), h3 = f2bf(v.w);
    u16 l0 = f2bf(v.x - bf2f(h0)), l1 = f2bf(v.y - bf2f(h1));
    u16 l2 = f2bf(v.z - bf2f(h2)), l3 = f2bf(v.w - bf2f(h3));
    u16* dst = Xcat + (size_t)row * 256 + c4;
    *(u32*)(dst)       = (u32)h0 | ((u32)h1 << 16);
    *(u32*)(dst + 2)   = (u32)h2 | ((u32)h3 << 16);
    *(u32*)(dst + 128) = (u32)l0 | ((u32)l1 << 16);
    *(u32*)(dst + 130) = (u32)l2 | ((u32)l3 << 16);
}

__global__ void k_split_w(const float* __restrict__ W0, const float* __restrict__ W1,
                          const float* __restrict__ W2, const float* __restrict__ W3,
                          u16* __restrict__ Wcat) {
    const int l = blockIdx.y;
    const float* W = (l == 0) ? W0 : (l == 1) ? W1 : (l == 2) ? W2 : W3;
    const int rows = (l == 3) ? 64 : 128;
    int idx = blockIdx.x * 256 + threadIdx.x;
    if (idx >= rows * 128) return;
    const int r = idx >> 7, c = idx & 127;
    float v = W[idx];
    u16 h = f2bf(v);
    u16 lo = f2bf(v - bf2f(h));
    u16* dst = Wcat + (size_t)l * 128 * 256 + (size_t)r * 256 + c;
    dst[0]   = h;
    dst[128] = lo;
}

// ---------- MFMA GEMM: H[Mpad,Dout] = Xcat[Mpad,256] @ Wcat[Dout,256]^T ----------
template <int FM>
__global__ __launch_bounds__(256)
void k_gemm_mfma(const u16* __restrict__ Xcat, const u16* __restrict__ Wcat,
                 float* __restrict__ H) {
    constexpr int Dout = (FM == 4) ? 128 : 64;
    const int tid = threadIdx.x;
    const int wave = tid >> 6, lane = tid & 63;
    const int wm = (FM == 4) ? (wave >> 1) : wave;
    const int wn = (FM == 4) ? (wave & 1) : 0;
    const int row_base = blockIdx.x * 128 + wm * (FM * 16);
    const int col_base = wn * 64;
    const int lr = lane & 15;
    const int kg = lane >> 4;       // k-group (0..3)

    f32x4 acc[FM][4] = {};

    #pragma unroll 2
    for (int ks = 0; ks < 8; ++ks) {
        const int k0 = ks * 32 + kg * 8;
        bf16x8 a[FM], b[4];
        #pragma unroll
        for (int i = 0; i < FM; ++i)
            a[i] = *(const bf16x8*)(Xcat + (size_t)(row_base + i * 16 + lr) * 256 + k0);
        #pragma unroll
        for (int j = 0; j < 4; ++j)
            b[j] = *(const bf16x8*)(Wcat + (size_t)(col_base + j * 16 + lr) * 256 + k0);
        #pragma unroll
        for (int i = 0; i < FM; ++i)
            #pragma unroll
            for (int j = 0; j < 4; ++j)
                acc[i][j] = __builtin_amdgcn_mfma_f32_16x16x32_bf16(a[i], b[j], acc[i][j], 0, 0, 0);
    }

    #pragma unroll
    for (int i = 0; i < FM; ++i) {
        const int r0 = row_base + i * 16 + kg * 4;
        #pragma unroll
        for (int j = 0; j < 4; ++j) {
            const int c = col_base + j * 16 + lr;
            #pragma unroll
            for (int q = 0; q < 4; ++q)
                H[(size_t)(r0 + q) * Dout + c] = acc[i][j][q];
        }
    }
}

// ---------- gather-aggregate + bias (+relu) ----------
// One wave per node. (src,w) batch-preloaded + shfl-broadcast. Edge batches are
// PADDED to a multiple of 16 with (s=0, w=0) dummies so all gather loads issue
// in parallel (no serial tail; dummy loads hit the L1-hot row 0, FMA adds 0).
template <int D, int OUT_MODE>
__global__ void k_agg_gather(const float* __restrict__ H, const float* __restrict__ dinv,
                             const int* __restrict__ rp, const int* __restrict__ csr_src,
                             const float* __restrict__ csr_w, const float* __restrict__ b,
                             void* __restrict__ out, int N, int E) {
    const int node = blockIdx.x * 4 + (threadIdx.x >> 6);
    const int lane = threadIdx.x & 63;
    if (node >= N) return;
    const int beg = rp[node];
    const int end = (node == N - 1) ? E : rp[node + 1];
    const int deg = end - beg;
    const float di = dinv[node];
    const double wself = (double)di * (double)di;

    if (D == 128) {
        const int d0 = lane * 2;
        double a0[8] = {}, a1[8] = {};
        {
            const float2 hs = *(const float2*)(H + (size_t)node * D + d0);
            a0[0] = wself * hs.x; a1[0] = wself * hs.y;
        }
        for (int base = 0; base < deg; base += 64) {
            const int m = min(64, deg - base);
            int s_l = 0; float w_l = 0.f;
            if (lane < m) {
                s_l = csr_src[beg + base + lane];
                w_l = csr_w[beg + base + lane];
            }
            const int m16 = (m + 15) & ~15;
            for (int j = 0; j < m16; j += 16) {
                int s[16]; float w[16];
                #pragma unroll
                for (int q = 0; q < 16; ++q) {
                    s[q] = __shfl(s_l, j + q);
                    w[q] = __shfl(w_l, j + q);
                }
                float2 h[16];
                #pragma unroll
                for (int q = 0; q < 16; ++q)
                    h[q] = *(const float2*)(H + (size_t)s[q] * D + d0);
                #pragma unroll
                for (int q = 0; q < 16; ++q) {
                    a0[q & 7] += (double)w[q] * h[q].x;
                    a1[q & 7] += (double)w[q] * h[q].y;
                }
            }
        }
        double A0 = ((a0[0] + a0[1]) + (a0[2] + a0[3])) + ((a0[4] + a0[5]) + (a0[6] + a0[7]));
        double A1 = ((a1[0] + a1[1]) + (a1[2] + a1[3])) + ((a1[4] + a1[5]) + (a1[6] + a1[7]));
        float v0 = (float)(A0 + (double)b[d0]);
        float v1 = (float)(A1 + (double)b[d0 + 1]);
        if (OUT_MODE == 1) {
            v0 = fmaxf(v0, 0.0f); v1 = fmaxf(v1, 0.0f);
            const u16 h0 = f2bf(v0), h1 = f2bf(v1);
            const u16 l0 = f2bf(v0 - bf2f(h0)), l1 = f2bf(v1 - bf2f(h1));
            u16* xc = (u16*)out + (size_t)node * 256 + d0;
            *(u32*)(xc)       = (u32)h0 | ((u32)h1 << 16);
            *(u32*)(xc + 128) = (u32)l0 | ((u32)l1 << 16);
        } else {
            *(float2*)((float*)out + (size_t)node * D + d0) = make_float2(v0, v1);
        }
    } else {  // D == 64: two 32-lane halves; each half owns 8 of every 16 edges
        const int half = lane >> 5;
        const int l32 = lane & 31;
        const int d0 = l32 * 2;
        double a0[8] = {}, a1[8] = {};
        if (half == 0) {
            const float2 hs = *(const float2*)(H + (size_t)node * D + d0);
            a0[0] = wself * hs.x; a1[0] = wself * hs.y;
        }
        for (int base = 0; base < deg; base += 64) {
            const int m = min(64, deg - base);
            int s_l = 0; float w_l = 0.f;
            if (lane < m) {
                s_l = csr_src[beg + base + lane];
                w_l = csr_w[beg + base + lane];
            }
            const int m16 = (m + 15) & ~15;
            for (int j = 0; j < m16; j += 16) {
                int s[8]; float w[8];
                #pragma unroll
                for (int q = 0; q < 8; ++q) {
                    const int e = j + 2 * q + half;
                    s[q] = __shfl(s_l, e);
                    w[q] = __shfl(w_l, e);
                }
                float2 h[8];
                #pragma unroll
                for (int q = 0; q < 8; ++q)
                    h[q] = *(const float2*)(H + (size_t)s[q] * D + d0);
                #pragma unroll
                for (int q = 0; q < 8; ++q) {
                    a0[q] += (double)w[q] * h[q].x;
                    a1[q] += (double)w[q] * h[q].y;
                }
            }
        }
        double A0 = ((a0[0] + a0[1]) + (a0[2] + a0[3])) + ((a0[4] + a0[5]) + (a0[6] + a0[7]));
        double A1 = ((a1[0] + a1[1]) + (a1[2] + a1[3])) + ((a1[4] + a1[5]) + (a1[6] + a1[7]));
        A0 += __shfl_xor(A0, 32);
        A1 += __shfl_xor(A1, 32);
        if (half == 0) {
            float v0 = (float)(A0 + (double)b[d0]);
            float v1 = (float)(A1 + (double)b[d0 + 1]);
            *(float2*)((float*)out + (size_t)node * D + d0) = make_float2(v0, v1);
        }
    }
}

extern "C" void kernel_launch(void* const* d_in, const int* in_sizes, int n_in,
                              void* d_out, int out_size, void* d_ws, size_t ws_size,
                              hipStream_t stream) {
    const float* x  = (const float*)d_in[0];
    const int*   ei = (const int*)d_in[1];
    const float* W[4] = {(const float*)d_in[2], (const float*)d_in[4],
                         (const float*)d_in[6], (const float*)d_in[8]};
    const float* B[4] = {(const float*)d_in[3], (const float*)d_in[5],
                         (const float*)d_in[7], (const float*)d_in[9]};
    const int N = in_sizes[0] / D_INF;
    const int E = in_sizes[1] / 2;
    const int Mpad = (N + 127) & ~127;
    const int* row  = ei;        // sources
    const int* colv = ei + E;    // targets

    // workspace carve-up
    size_t nPad = ((size_t)N + 255) & ~(size_t)255;
    size_t ePad = ((size_t)E + 255) & ~(size_t)255;
    float* dinv    = (float*)d_ws;
    int*   cnt     = (int*)(dinv + nPad);
    int*   bsum    = cnt + nPad;
    int*   rp      = bsum + 256;
    int*   csr_src = rp + nPad;
    float* csr_w   = (float*)(csr_src + ePad);
    float* Hbuf    = csr_w + ePad;                       // [Mpad][128] f32
    u16*   Xcat    = (u16*)(Hbuf + (size_t)Mpad * 128);  // [Mpad][256] bf16
    u16*   Wcat    = Xcat + (size_t)Mpad * 256;          // 4 x [128][256] bf16

    const int TB = 256;
    int nbN = (N + TB - 1) / TB;
    int nbE = (E + TB - 1) / TB;

    // --- CSR build ---
    k_zero_i32<<<nbN, TB, 0, stream>>>(cnt, N);
    k_count<<<nbE, TB, 0, stream>>>(colv, cnt, E);
    k_scan_block<<<nbN, TB, 0, stream>>>(cnt, rp, bsum, dinv, N);   // + dinv + cnt reset
    k_scan_bsum<<<1, 256, 0, stream>>>(bsum, nbN);
    k_scan_add2<<<nbN, TB, 0, stream>>>(rp, bsum, N);
    k_scatter<<<nbE, TB, 0, stream>>>(row, colv, dinv, rp, cnt, csr_src, csr_w, E);

    // --- bf16 splits ---
    k_split_x<<<(Mpad * 32 + TB - 1) / TB, TB, 0, stream>>>(x, Xcat, N, Mpad);
    {
        dim3 g(64, 4);
        k_split_w<<<g, TB, 0, stream>>>(W[0], W[1], W[2], W[3], Wcat);
    }

    const int aggGrid = (N + 3) / 4;
    const int gemmGrid = Mpad / 128;

    // layers 0..2 : GEMM(128) -> gather -> Xcat(bf16 split)
    for (int l = 0; l < 3; ++l) {
        k_gemm_mfma<4><<<gemmGrid, 256, 0, stream>>>(Xcat, Wcat + (size_t)l * 128 * 256, Hbuf);
        k_agg_gather<128, 1><<<aggGrid, TB, 0, stream>>>(Hbuf, dinv, rp, csr_src, csr_w,
                                                         B[l], (void*)Xcat, N, E);
    }
    // layer 3 : GEMM(64) -> gather -> d_out (f32)
    k_gemm_mfma<2><<<gemmGrid, 256, 0, stream>>>(Xcat, Wcat + (size_t)3 * 128 * 256, Hbuf);
    k_agg_gather<64, 0><<<aggGrid, TB, 0, stream>>>(Hbuf, dinv, rp, csr_src, csr_w,
                                                    B[3], d_out, N, E);
}